// Round 16
// baseline (345.256 us; speedup 1.0000x reference)
//
#include <hip/hip_runtime.h>

#define F_IN 512
#define HDIM 64
#define RSHIFT 7
#define RWIDTH 128
#define MAXNB 1024
#define CHUNK 4096

typedef _Float16 f16;
typedef _Float16 f16x2 __attribute__((ext_vector_type(2)));
typedef _Float16 f16x8 __attribute__((ext_vector_type(8)));
typedef float f32x4 __attribute__((ext_vector_type(4)));

#define GLOAD_LDS16(src, dst)                                                        \
    __builtin_amdgcn_global_load_lds((const __attribute__((address_space(1))) void*)(src), \
                                     (__attribute__((address_space(3))) void*)(dst), 16, 0, 0)

// wsum[k] = sum_j linW[j][k]; wsum[64] = sum_j linB[j]
__global__ void prep_kernel(const float* __restrict__ linW,
                            const float* __restrict__ linB,
                            float* __restrict__ wsum) {
    int k = threadIdx.x;
    float s = 0.f;
    for (int j = 0; j < HDIM; ++j) s += linW[j * HDIM + k];
    wsum[k] = s;
    if (k == 0) {
        float b = 0.f;
        for (int j = 0; j < HDIM; ++j) b += linB[j];
        wsum[HDIM] = b;
    }
}

// fc_weight as f16 in B-fragment order:
// wf[((s*4 + c)*64 + lane)*8 + j] = W[c*16 + (lane&15)][s*32 + (lane>>4)*8 + j]
__global__ __launch_bounds__(256) void prep_w16_kernel(const float* __restrict__ W,
                                                       f16* __restrict__ wf) {
    int t = blockIdx.x * 256 + threadIdx.x;   // 0..4095
    int s = t >> 8;
    int c = (t >> 6) & 3;
    int l = t & 63;
    int row = c * 16 + (l & 15);
    int kb = s * 32 + ((l >> 4) << 3);
#pragma unroll
    for (int j = 0; j < 8; ++j)
        wf[(size_t)t * 8 + j] = (f16)W[row * F_IN + kb + j];
}

__global__ void zero_int_kernel(int* __restrict__ p, int n) {
    int i = blockIdx.x * blockDim.x + threadIdx.x;
    if (i < n) p[i] = 0;
}

// bucket histogram, LDS-pre-aggregated
__global__ __launch_bounds__(256) void bhist_kernel(const int* __restrict__ row,
                                                    int* __restrict__ bh,
                                                    int n_edges, int NB) {
    __shared__ int lh[MAXNB];
    for (int i = threadIdx.x; i < NB; i += 256) lh[i] = 0;
    __syncthreads();
    for (int e = blockIdx.x * 256 + threadIdx.x; e < n_edges; e += gridDim.x * 256)
        atomicAdd(&lh[row[e] >> RSHIFT], 1);
    __syncthreads();
    for (int i = threadIdx.x; i < NB; i += 256)
        if (lh[i]) atomicAdd(&bh[i], lh[i]);
}

// one block: exclusive scan of bh -> boff; init gcur; ptr[n_nodes] = n_edges
__global__ __launch_bounds__(1024) void bscan_kernel(const int* __restrict__ bh,
                                                     int* __restrict__ boff,
                                                     int* __restrict__ gcur,
                                                     int* __restrict__ ptr,
                                                     int NB, int n_nodes, int n_edges) {
    __shared__ int s[1024];
    const int t = threadIdx.x;
    int v = (t < NB) ? bh[t] : 0;
    s[t] = v;
    __syncthreads();
#pragma unroll
    for (int off = 1; off < 1024; off <<= 1) {
        int x = (t >= off) ? s[t - off] : 0;
        __syncthreads();
        s[t] += x;
        __syncthreads();
    }
    if (t < NB) {
        int o = s[t] - v;
        boff[t] = o;
        gcur[t] = o;
    }
    if (t == NB) boff[NB] = n_edges;
    if (t == 0) ptr[n_nodes] = n_edges;
}

// partition: per-block counting sort by bucket in LDS, append runs to global regions.
// record: (w_bits, col<<7 | row&127)
__global__ __launch_bounds__(256) void part_kernel(const int* __restrict__ row,
                                                   const int* __restrict__ col,
                                                   const float* __restrict__ w,
                                                   int* __restrict__ gcur,
                                                   int2* __restrict__ etmp,
                                                   int n_edges, int NB) {
    __shared__ int2 stg[CHUNK];             // 32 KB
    __shared__ unsigned short sbin[CHUNK];  // 8 KB
    __shared__ int lh[MAXNB];
    __shared__ int lofs[MAXNB];
    __shared__ int psum[256];
    const int t = threadIdx.x;
    const int base = blockIdx.x * CHUNK;
    const int cnt = min(CHUNK, n_edges - base);

    for (int i = t; i < NB; i += 256) lh[i] = 0;
    __syncthreads();
    for (int i = t; i < cnt; i += 256)
        atomicAdd(&lh[row[base + i] >> RSHIFT], 1);
    __syncthreads();
    int loc[4];
    int s0 = 0;
#pragma unroll
    for (int j = 0; j < 4; ++j) {
        int b = t * 4 + j;
        int c = (b < NB) ? lh[b] : 0;
        loc[j] = s0;
        s0 += c;
    }
    psum[t] = s0;
    __syncthreads();
#pragma unroll
    for (int off = 1; off < 256; off <<= 1) {
        int x = (t >= off) ? psum[t - off] : 0;
        __syncthreads();
        psum[t] += x;
        __syncthreads();
    }
    int pbase = psum[t] - s0;
#pragma unroll
    for (int j = 0; j < 4; ++j) {
        int b = t * 4 + j;
        if (b < NB) lofs[b] = pbase + loc[j];
    }
    __syncthreads();
    for (int i = t; i < cnt; i += 256) {
        int r = row[base + i];
        int b = r >> RSHIFT;
        int p = atomicAdd(&lofs[b], 1);
        stg[p] = make_int2(__float_as_int(w[base + i]),
                           (col[base + i] << RSHIFT) | (r & (RWIDTH - 1)));
        sbin[p] = (unsigned short)b;
    }
    __syncthreads();
    for (int b = t; b < NB; b += 256) {
        int c = lh[b];
        if (c) {
            int lstart = lofs[b] - c;
            int gb = atomicAdd(&gcur[b], c);
            lh[b] = gb - lstart;
        }
    }
    __syncthreads();
    for (int p = t; p < cnt; p += 256) {
        int b = sbin[p];
        etmp[lh[b] + p] = stg[p];
    }
}

// per-bucket counting sort -> full CSR order; write ptr. record out: (w_bits, col)
__global__ __launch_bounds__(256) void bsort_kernel(const int* __restrict__ boff,
                                                    const int2* __restrict__ etmp,
                                                    int2* __restrict__ ebin,
                                                    int* __restrict__ ptr,
                                                    int n_nodes) {
    __shared__ int nh[RWIDTH], lo[RWIDTH], lc[RWIDTH];
    const int b = blockIdx.x;
    const int t = threadIdx.x;
    const int e0 = boff[b], e1 = boff[b + 1];
    const int cnt = e1 - e0;
    if (t < RWIDTH) nh[t] = 0;
    __syncthreads();
    for (int i = t; i < cnt; i += 256)
        atomicAdd(&nh[etmp[e0 + i].y & (RWIDTH - 1)], 1);
    __syncthreads();
    if (t < RWIDTH) lo[t] = nh[t];
    __syncthreads();
    for (int off = 1; off < RWIDTH; off <<= 1) {
        int x = 0;
        if (t < RWIDTH && t >= off) x = lo[t - off];
        __syncthreads();
        if (t < RWIDTH) lo[t] += x;
        __syncthreads();
    }
    if (t < RWIDTH) {
        int ex = lo[t] - nh[t];               // exclusive
        lc[t] = ex;
        int node = b * RWIDTH + t;
        if (node < n_nodes) ptr[node] = e0 + ex;
    }
    __syncthreads();
    for (int i = t; i < cnt; i += 256) {
        int2 r = etmp[e0 + i];
        int p = atomicAdd(&lc[r.y & (RWIDTH - 1)], 1);
        ebin[e0 + p] = make_int2(r.x, r.y >> RSHIFT);
    }
}

// Both GCN fc passes per block over 64 rows (best-known config, ~138 us).
__global__ __launch_bounds__(256) void gemm_both_kernel(const float* __restrict__ X1,
                                                        const float* __restrict__ X2,
                                                        const f16* __restrict__ wf,
                                                        f16* __restrict__ H,
                                                        int n_nodes) {
    __shared__ float4 tile_v[1024];   // 16 KB (epilogue tile)
    f16* tile = (f16*)tile_v;
    const int t = threadIdx.x;
    const int l = t & 63;
    const int w = t >> 6;
    const int m0 = blockIdx.x * 64;
    int arow = m0 + w * 16 + (l & 15);
    if (arow >= n_nodes) arow = n_nodes - 1;
    const int g = l >> 4;
    const float* xp1 = X1 + (size_t)arow * F_IN + (g << 3);
    const float* xp2 = X2 + (size_t)arow * F_IN + (g << 3);
    const f16x8* wfv = reinterpret_cast<const f16x8*>(wf) + l;

    f32x4 a00 = {}, a01 = {}, a02 = {}, a03 = {};
    f32x4 a10 = {}, a11 = {}, a12 = {}, a13 = {};

    float4 xa0A, xb0A, xa1A, xb1A; f16x8 B0A, B1A, B2A, B3A;
    float4 xa0B, xb0B, xa1B, xb1B; f16x8 B0B, B1B, B2B, B3B;

#define LD_X(d0a, d0b, d1a, d1b, c)                                   \
    d0a = *reinterpret_cast<const float4*>(xp1 + (c) * 32);           \
    d0b = *reinterpret_cast<const float4*>(xp1 + (c) * 32 + 4);       \
    d1a = *reinterpret_cast<const float4*>(xp2 + (c) * 32);           \
    d1b = *reinterpret_cast<const float4*>(xp2 + (c) * 32 + 4);

#define LD_B(d0, d1, d2, d3, c)                                       \
    {                                                                 \
        const f16x8* bp = wfv + (size_t)(c) * 256;                    \
        d0 = bp[0]; d1 = bp[64]; d2 = bp[128]; d3 = bp[192];          \
    }

#define COMP(xa0, xb0, xa1, xb1, b0, b1, b2, b3)                              \
    {                                                                         \
        f16x8 a;                                                              \
        a[0] = (f16)xa0.x; a[1] = (f16)xa0.y; a[2] = (f16)xa0.z;              \
        a[3] = (f16)xa0.w; a[4] = (f16)xb0.x; a[5] = (f16)xb0.y;              \
        a[6] = (f16)xb0.z; a[7] = (f16)xb0.w;                                 \
        a00 = __builtin_amdgcn_mfma_f32_16x16x32_f16(a, b0, a00, 0, 0, 0);    \
        a01 = __builtin_amdgcn_mfma_f32_16x16x32_f16(a, b1, a01, 0, 0, 0);    \
        a02 = __builtin_amdgcn_mfma_f32_16x16x32_f16(a, b2, a02, 0, 0, 0);    \
        a03 = __builtin_amdgcn_mfma_f32_16x16x32_f16(a, b3, a03, 0, 0, 0);    \
        a[0] = (f16)xa1.x; a[1] = (f16)xa1.y; a[2] = (f16)xa1.z;              \
        a[3] = (f16)xa1.w; a[4] = (f16)xb1.x; a[5] = (f16)xb1.y;              \
        a[6] = (f16)xb1.z; a[7] = (f16)xb1.w;                                 \
        a10 = __builtin_amdgcn_mfma_f32_16x16x32_f16(a, b0, a10, 0, 0, 0);    \
        a11 = __builtin_amdgcn_mfma_f32_16x16x32_f16(a, b1, a11, 0, 0, 0);    \
        a12 = __builtin_amdgcn_mfma_f32_16x16x32_f16(a, b2, a12, 0, 0, 0);    \
        a13 = __builtin_amdgcn_mfma_f32_16x16x32_f16(a, b3, a13, 0, 0, 0);    \
    }

    LD_X(xa0A, xb0A, xa1A, xb1A, 0)
    LD_B(B0A, B1A, B2A, B3A, 0)
#pragma unroll
    for (int cc = 0; cc < 8; ++cc) {
        const int c1 = 2 * cc + 1;
        LD_X(xa0B, xb0B, xa1B, xb1B, c1)
        LD_B(B0B, B1B, B2B, B3B, c1)
        COMP(xa0A, xb0A, xa1A, xb1A, B0A, B1A, B2A, B3A)
        if (cc < 7) {
            LD_X(xa0A, xb0A, xa1A, xb1A, c1 + 1)
            LD_B(B0A, B1A, B2A, B3A, c1 + 1)
        }
        COMP(xa0B, xb0B, xa1B, xb1B, B0B, B1B, B2B, B3B)
    }
#undef LD_X
#undef LD_B
#undef COMP

    {
        const int colj = l & 15;
        const int rbase = w * 16 + g * 4;
        __syncthreads();
#pragma unroll
        for (int j = 0; j < 4; ++j) {
            f16* tp = tile + (rbase + j) * 128 + colj * 2;
            tp[0]  = (f16)a00[j];
            tp[1]  = (f16)a10[j];
            tp[32] = (f16)a01[j];
            tp[33] = (f16)a11[j];
            tp[64] = (f16)a02[j];
            tp[65] = (f16)a12[j];
            tp[96] = (f16)a03[j];
            tp[97] = (f16)a13[j];
        }
        __syncthreads();
        const int row = t >> 2;
        const int gm = m0 + row;
        if (gm < n_nodes) {
            const float4* sp = reinterpret_cast<const float4*>((char*)tile + row * 256 + (t & 3) * 64);
            float4* dp = reinterpret_cast<float4*>((char*)H + (size_t)gm * 256 + (t & 3) * 64);
#pragma unroll
            for (int q = 0; q < 4; ++q) dp[q] = sp[q];
        }
    }
}

// per-node wave gather, BOTH passes at once; 4-deep load pipeline.
__global__ __launch_bounds__(256) void agg_both_kernel(const int* __restrict__ ptr,
                                                       const int2* __restrict__ ebin,
                                                       const f16* __restrict__ h,
                                                       const float* __restrict__ gbias,
                                                       const float* __restrict__ wsum,
                                                       const float* __restrict__ prelu_a,
                                                       float* __restrict__ z,
                                                       int n_nodes) {
    const int lane = threadIdx.x & 63;
    const int wv = threadIdx.x >> 6;
    const int n = blockIdx.x * 4 + wv;
    if (n >= n_nodes) return;
    const f16x2* hv = reinterpret_cast<const f16x2*>(h) + lane;
    const int p0 = __builtin_amdgcn_readfirstlane(ptr[n]);
    const int p1 = __builtin_amdgcn_readfirstlane(ptr[n + 1]);
    float acc1 = 0.f, acc2 = 0.f;
    int i = p0;
    for (; i + 3 < p1; i += 4) {
        int2 e0 = ebin[i];
        int2 e1 = ebin[i + 1];
        int2 e2 = ebin[i + 2];
        int2 e3 = ebin[i + 3];
        f16x2 h0 = hv[(size_t)e0.y * HDIM];
        f16x2 h1 = hv[(size_t)e1.y * HDIM];
        f16x2 h2 = hv[(size_t)e2.y * HDIM];
        f16x2 h3 = hv[(size_t)e3.y * HDIM];
        float w0 = __int_as_float(e0.x), w1 = __int_as_float(e1.x);
        float w2 = __int_as_float(e2.x), w3 = __int_as_float(e3.x);
        acc1 = fmaf(w0, (float)h0[0], acc1);
        acc2 = fmaf(w0, (float)h0[1], acc2);
        acc1 = fmaf(w1, (float)h1[0], acc1);
        acc2 = fmaf(w1, (float)h1[1], acc2);
        acc1 = fmaf(w2, (float)h2[0], acc1);
        acc2 = fmaf(w2, (float)h2[1], acc2);
        acc1 = fmaf(w3, (float)h3[0], acc1);
        acc2 = fmaf(w3, (float)h3[1], acc2);
    }
    for (; i < p1; ++i) {
        int2 e0 = ebin[i];
        f16x2 h0 = hv[(size_t)e0.y * HDIM];
        float w0 = __int_as_float(e0.x);
        acc1 = fmaf(w0, (float)h0[0], acc1);
        acc2 = fmaf(w0, (float)h0[1], acc2);
    }
    const float a = prelu_a[0];
    const float gb = gbias[lane];
    const float wl = wsum[lane];
    float v1 = acc1 + gb;
    float v2 = acc2 + gb;
    v1 = (v1 >= 0.f) ? v1 : a * v1;
    v2 = (v2 >= 0.f) ? v2 : a * v2;
    float q1 = v1 * wl;
    float q2 = v2 * wl;
#pragma unroll
    for (int m = 32; m >= 1; m >>= 1) {
        q1 += __shfl_xor(q1, m, 64);
        q2 += __shfl_xor(q2, m, 64);
    }
    if (lane == 0) {
        z[n] = q1 + wsum[HDIM];
        z[n + n_nodes] = q2 + wsum[HDIM];
    }
}

// ---------------- DIAGNOSTICS (ablation of the gemm's load path) ----------------

// diagB: gemm A-access pattern (16 rows x 128B per wave-instr), plain VGPR loads,
// deep unroll, NO MFMA. Tests: pattern + compiler pipelining without matrix ops.
__global__ __launch_bounds__(256) void diagB_kernel(const float* __restrict__ X,
                                                    float* __restrict__ sink, int n_tiles) {
    const int t = threadIdx.x, l = t & 63, w = t >> 6, g = l >> 4;
    const int r = w * 16 + (l & 15);
    float acc = 0.f;
    for (int tile = blockIdx.x; tile < n_tiles; tile += gridDim.x) {
        const float* xp = X + (size_t)(tile * 64 + r) * F_IN + g * 8;
#pragma unroll
        for (int c = 0; c < 16; ++c) {
            float4 a = *reinterpret_cast<const float4*>(xp + c * 32);
            float4 b = *reinterpret_cast<const float4*>(xp + c * 32 + 4);
            acc += a.x + a.y + a.z + a.w + b.x + b.y + b.z + b.w;
        }
    }
#pragma unroll
    for (int m = 32; m >= 1; m >>= 1) acc += __shfl_xor(acc, m, 64);
    if (l == 0) sink[blockIdx.x * 4 + w] = acc;
}

// diagC: exact gload_lds staging loop WITH per-chunk barrier, no compute.
// Tests: the async-DMA + barrier machinery alone.
__global__ __launch_bounds__(256) void diagC_kernel(const float* __restrict__ X,
                                                    float* __restrict__ sink, int n_tiles) {
    __shared__ float4 lds4[1024];   // 16 KB
    char* xs = (char*)lds4;
    const int t = threadIdx.x, l = t & 63, w = t >> 6;
    float acc = 0.f;
    for (int tile = blockIdx.x; tile < n_tiles; tile += gridDim.x) {
        const char* sb = (const char*)(X + (size_t)(tile * 64 + l) * F_IN) + w * 32;
#pragma unroll
        for (int c = 0; c < 16; ++c) {
            GLOAD_LDS16(sb + c * 128,      xs + ((c & 1) * 8192) + w * 2048);
            GLOAD_LDS16(sb + c * 128 + 16, xs + ((c & 1) * 8192) + w * 2048 + 1024);
            __syncthreads();
        }
        acc += *reinterpret_cast<float*>(xs + t * 16);
    }
#pragma unroll
    for (int m = 32; m >= 1; m >>= 1) acc += __shfl_xor(acc, m, 64);
    if (l == 0) sink[blockIdx.x * 4 + w] = acc;
}

// diagD: pure gload_lds issue, NO barriers until the very end.
// Tests: max DMA issue/queue throughput (LDS data is garbage; BW probe only).
__global__ __launch_bounds__(256) void diagD_kernel(const float* __restrict__ X,
                                                    float* __restrict__ sink, int n_tiles) {
    __shared__ float4 lds4[1024];   // 16 KB
    char* xs = (char*)lds4;
    const int t = threadIdx.x, l = t & 63, w = t >> 6;
    for (int tile = blockIdx.x; tile < n_tiles; tile += gridDim.x) {
        const char* sb = (const char*)(X + (size_t)(tile * 64 + l) * F_IN) + w * 32;
#pragma unroll
        for (int c = 0; c < 16; ++c) {
            GLOAD_LDS16(sb + c * 128,      xs + ((c & 1) * 8192) + w * 2048);
            GLOAD_LDS16(sb + c * 128 + 16, xs + ((c & 1) * 8192) + w * 2048 + 1024);
        }
    }
    __syncthreads();
    if (t == 0) sink[blockIdx.x] = *reinterpret_cast<float*>(xs);
}

extern "C" void kernel_launch(void* const* d_in, const int* in_sizes, int n_in,
                              void* d_out, int out_size, void* d_ws, size_t ws_size,
                              hipStream_t stream) {
    const float* x1    = (const float*)d_in[0];
    const float* x2    = (const float*)d_in[1];
    const int*   erow  = (const int*)d_in[2];
    const int*   ecol  = (const int*)d_in[3];
    const float* ew    = (const float*)d_in[4];
    const float* fcw   = (const float*)d_in[5];
    const float* gbias = (const float*)d_in[6];
    const float* pa    = (const float*)d_in[7];
    const float* linw  = (const float*)d_in[8];
    const float* linb  = (const float*)d_in[9];
    float* out = (float*)d_out;

    const int n_nodes = in_sizes[0] / F_IN;   // 100000
    const int n_edges = in_sizes[2];          // 1600000
    const int NB = (n_nodes + RWIDTH - 1) >> RSHIFT;   // 782

    // workspace layout
    f16*   h16  = (f16*)d_ws;                           // n_nodes*128 f16 (both passes)
    f16*   wf   = h16 + (size_t)n_nodes * 2 * HDIM;     // 64*512 f16
    int2*  etmp = (int2*)(wf + 64 * F_IN);              // n_edges int2
    int2*  ebin = etmp + n_edges;                       // n_edges int2
    int*   bh   = (int*)(ebin + n_edges);               // MAXNB
    int*   boff = bh + MAXNB;                           // MAXNB+1
    int*   gcur = boff + MAXNB + 1;                     // MAXNB
    int*   ptr  = gcur + MAXNB;                         // n_nodes+1
    float* wsum = (float*)(ptr + n_nodes + 1);          // 65 f32
    float* sinkB = wsum + 65;                           // 8192 f32
    float* sinkC = sinkB + 8192;                        // 8192 f32
    float* sinkD = sinkC + 8192;                        // 8192 f32

    prep_kernel<<<1, 64, 0, stream>>>(linw, linb, wsum);
    prep_w16_kernel<<<16, 256, 0, stream>>>(fcw, wf);

    zero_int_kernel<<<(NB + 255) / 256, 256, 0, stream>>>(bh, NB);
    bhist_kernel<<<256, 256, 0, stream>>>(erow, bh, n_edges, NB);
    bscan_kernel<<<1, 1024, 0, stream>>>(bh, boff, gcur, ptr, NB, n_nodes, n_edges);
    part_kernel<<<(n_edges + CHUNK - 1) / CHUNK, 256, 0, stream>>>(erow, ecol, ew, gcur,
                                                                   etmp, n_edges, NB);
    bsort_kernel<<<NB, 256, 0, stream>>>(boff, etmp, ebin, ptr, n_nodes);

    const int gemm_grid = (n_nodes + 63) / 64;
    const int fin_grid  = (n_nodes + 3) / 4;
    gemm_both_kernel<<<gemm_grid, 256, 0, stream>>>(x1, x2, wf, h16, n_nodes);
    agg_both_kernel<<<fin_grid, 256, 0, stream>>>(ptr, ebin, h16, gbias, wsum, pa,
                                                  out, n_nodes);

    // ---- diagnostics (each streams X1 once; results -> scratch sinks) ----
    const int n_tiles = n_nodes / 64;   // 1562 full tiles (no OOB)
    diagB_kernel<<<n_tiles, 256, 0, stream>>>(x1, sinkB, n_tiles);
    diagC_kernel<<<n_tiles, 256, 0, stream>>>(x1, sinkC, n_tiles);
    diagD_kernel<<<n_tiles, 256, 0, stream>>>(x1, sinkD, n_tiles);
}

// Round 18
// 251.685 us; speedup vs baseline: 1.3718x; 1.3718x over previous
//
#include <hip/hip_runtime.h>

#define F_IN 512
#define HDIM 64
#define RSHIFT 7
#define RWIDTH 128
#define MAXNB 1024
#define CHUNK 4096

typedef _Float16 f16;
typedef _Float16 f16x2 __attribute__((ext_vector_type(2)));
typedef _Float16 f16x8 __attribute__((ext_vector_type(8)));
typedef float f32x4 __attribute__((ext_vector_type(4)));

#define GLOAD_LDS16(src, dst)                                                        \
    __builtin_amdgcn_global_load_lds((const __attribute__((address_space(1))) void*)(src), \
                                     (__attribute__((address_space(3))) void*)(dst), 16, 0, 0)

// wsum[k] = sum_j linW[j][k]; wsum[64] = sum_j linB[j]
__global__ void prep_kernel(const float* __restrict__ linW,
                            const float* __restrict__ linB,
                            float* __restrict__ wsum) {
    int k = threadIdx.x;
    float s = 0.f;
    for (int j = 0; j < HDIM; ++j) s += linW[j * HDIM + k];
    wsum[k] = s;
    if (k == 0) {
        float b = 0.f;
        for (int j = 0; j < HDIM; ++j) b += linB[j];
        wsum[HDIM] = b;
    }
}

// fc_weight as f16 in B-fragment order:
// wf[((s*4 + c)*64 + lane)*8 + j] = W[c*16 + (lane&15)][s*32 + (lane>>4)*8 + j]
__global__ __launch_bounds__(256) void prep_w16_kernel(const float* __restrict__ W,
                                                       f16* __restrict__ wf) {
    int t = blockIdx.x * 256 + threadIdx.x;   // 0..4095
    int s = t >> 8;
    int c = (t >> 6) & 3;
    int l = t & 63;
    int row = c * 16 + (l & 15);
    int kb = s * 32 + ((l >> 4) << 3);
#pragma unroll
    for (int j = 0; j < 8; ++j)
        wf[(size_t)t * 8 + j] = (f16)W[row * F_IN + kb + j];
}

__global__ void zero_int_kernel(int* __restrict__ p, int n) {
    int i = blockIdx.x * blockDim.x + threadIdx.x;
    if (i < n) p[i] = 0;
}

// bucket histogram, LDS-pre-aggregated
__global__ __launch_bounds__(256) void bhist_kernel(const int* __restrict__ row,
                                                    int* __restrict__ bh,
                                                    int n_edges, int NB) {
    __shared__ int lh[MAXNB];
    for (int i = threadIdx.x; i < NB; i += 256) lh[i] = 0;
    __syncthreads();
    for (int e = blockIdx.x * 256 + threadIdx.x; e < n_edges; e += gridDim.x * 256)
        atomicAdd(&lh[row[e] >> RSHIFT], 1);
    __syncthreads();
    for (int i = threadIdx.x; i < NB; i += 256)
        if (lh[i]) atomicAdd(&bh[i], lh[i]);
}

// one block: exclusive scan of bh -> boff; init gcur; ptr[n_nodes] = n_edges
__global__ __launch_bounds__(1024) void bscan_kernel(const int* __restrict__ bh,
                                                     int* __restrict__ boff,
                                                     int* __restrict__ gcur,
                                                     int* __restrict__ ptr,
                                                     int NB, int n_nodes, int n_edges) {
    __shared__ int s[1024];
    const int t = threadIdx.x;
    int v = (t < NB) ? bh[t] : 0;
    s[t] = v;
    __syncthreads();
#pragma unroll
    for (int off = 1; off < 1024; off <<= 1) {
        int x = (t >= off) ? s[t - off] : 0;
        __syncthreads();
        s[t] += x;
        __syncthreads();
    }
    if (t < NB) {
        int o = s[t] - v;
        boff[t] = o;
        gcur[t] = o;
    }
    if (t == NB) boff[NB] = n_edges;
    if (t == 0) ptr[n_nodes] = n_edges;
}

// partition: per-block counting sort by bucket in LDS, append runs to global regions.
// record: (w_bits, col<<7 | row&127)
__global__ __launch_bounds__(256) void part_kernel(const int* __restrict__ row,
                                                   const int* __restrict__ col,
                                                   const float* __restrict__ w,
                                                   int* __restrict__ gcur,
                                                   int2* __restrict__ etmp,
                                                   int n_edges, int NB) {
    __shared__ int2 stg[CHUNK];             // 32 KB
    __shared__ unsigned short sbin[CHUNK];  // 8 KB
    __shared__ int lh[MAXNB];
    __shared__ int lofs[MAXNB];
    __shared__ int psum[256];
    const int t = threadIdx.x;
    const int base = blockIdx.x * CHUNK;
    const int cnt = min(CHUNK, n_edges - base);

    for (int i = t; i < NB; i += 256) lh[i] = 0;
    __syncthreads();
    for (int i = t; i < cnt; i += 256)
        atomicAdd(&lh[row[base + i] >> RSHIFT], 1);
    __syncthreads();
    int loc[4];
    int s0 = 0;
#pragma unroll
    for (int j = 0; j < 4; ++j) {
        int b = t * 4 + j;
        int c = (b < NB) ? lh[b] : 0;
        loc[j] = s0;
        s0 += c;
    }
    psum[t] = s0;
    __syncthreads();
#pragma unroll
    for (int off = 1; off < 256; off <<= 1) {
        int x = (t >= off) ? psum[t - off] : 0;
        __syncthreads();
        psum[t] += x;
        __syncthreads();
    }
    int pbase = psum[t] - s0;
#pragma unroll
    for (int j = 0; j < 4; ++j) {
        int b = t * 4 + j;
        if (b < NB) lofs[b] = pbase + loc[j];
    }
    __syncthreads();
    for (int i = t; i < cnt; i += 256) {
        int r = row[base + i];
        int b = r >> RSHIFT;
        int p = atomicAdd(&lofs[b], 1);
        stg[p] = make_int2(__float_as_int(w[base + i]),
                           (col[base + i] << RSHIFT) | (r & (RWIDTH - 1)));
        sbin[p] = (unsigned short)b;
    }
    __syncthreads();
    for (int b = t; b < NB; b += 256) {
        int c = lh[b];
        if (c) {
            int lstart = lofs[b] - c;
            int gb = atomicAdd(&gcur[b], c);
            lh[b] = gb - lstart;
        }
    }
    __syncthreads();
    for (int p = t; p < cnt; p += 256) {
        int b = sbin[p];
        etmp[lh[b] + p] = stg[p];
    }
}

// per-bucket counting sort -> full CSR order; write ptr. record out: (w_bits, col)
__global__ __launch_bounds__(256) void bsort_kernel(const int* __restrict__ boff,
                                                    const int2* __restrict__ etmp,
                                                    int2* __restrict__ ebin,
                                                    int* __restrict__ ptr,
                                                    int n_nodes) {
    __shared__ int nh[RWIDTH], lo[RWIDTH], lc[RWIDTH];
    const int b = blockIdx.x;
    const int t = threadIdx.x;
    const int e0 = boff[b], e1 = boff[b + 1];
    const int cnt = e1 - e0;
    if (t < RWIDTH) nh[t] = 0;
    __syncthreads();
    for (int i = t; i < cnt; i += 256)
        atomicAdd(&nh[etmp[e0 + i].y & (RWIDTH - 1)], 1);
    __syncthreads();
    if (t < RWIDTH) lo[t] = nh[t];
    __syncthreads();
    for (int off = 1; off < RWIDTH; off <<= 1) {
        int x = 0;
        if (t < RWIDTH && t >= off) x = lo[t - off];
        __syncthreads();
        if (t < RWIDTH) lo[t] += x;
        __syncthreads();
    }
    if (t < RWIDTH) {
        int ex = lo[t] - nh[t];               // exclusive
        lc[t] = ex;
        int node = b * RWIDTH + t;
        if (node < n_nodes) ptr[node] = e0 + ex;
    }
    __syncthreads();
    for (int i = t; i < cnt; i += 256) {
        int2 r = etmp[e0 + i];
        int p = atomicAdd(&lc[r.y & (RWIDTH - 1)], 1);
        ebin[e0 + p] = make_int2(r.x, r.y >> RSHIFT);
    }
}

// Both GCN fc passes per block over 64 rows, FUSED, manually-counted vmcnt
// pipeline (T3/T4): 4 LDS buffers x 20 KB {X1 8K | X2 8K | B 4K}, depth-3
// prefetch via global_load_lds (5 DMA ops/chunk), per-iteration
// asm s_waitcnt vmcnt(10) + RAW s_barrier — never vmcnt(0) until the tail.
// Staging: lane l stages row l; wave w stages k-slice bytes [w*32, w*32+32).
__global__ __launch_bounds__(256) void gemm_both_kernel(const float* __restrict__ X1,
                                                        const float* __restrict__ X2,
                                                        const f16* __restrict__ wf,
                                                        f16* __restrict__ H,
                                                        int n_nodes) {
    __shared__ char xs[81920];   // 4 x 20480
    const int t = threadIdx.x;
    const int l = t & 63;
    const int w = t >> 6;
    const int m0 = blockIdx.x * 64;
    int srow = m0 + l;
    if (srow >= n_nodes) srow = n_nodes - 1;       // clamp loads; stores guarded
    const char* sx1 = (const char*)(X1 + (size_t)srow * F_IN) + (w << 5);  // + wave k-slice
    const char* sx2 = (const char*)(X2 + (size_t)srow * F_IN) + (w << 5);
    const char* wfb = (const char*)wf;
    const int g = l >> 4;
    const int rl16 = (w * 16 + (l & 15)) * 16;

    f32x4 p00 = {}, p01 = {}, p02 = {}, p03 = {};   // pass 0 (X1), col-blocks 0..3
    f32x4 p10 = {}, p11 = {}, p12 = {}, p13 = {};   // pass 1 (X2)

// 5 async DMA ops per chunk; LDS layout per buffer: X1[0,8K) X2[8K,16K) B[16K,20K)
#define STAGE(c)                                                                  \
    {                                                                             \
        char* bb = xs + ((c) & 3) * 20480;                                        \
        GLOAD_LDS16(sx1 + (c) * 128,      bb + w * 2048);                         \
        GLOAD_LDS16(sx1 + (c) * 128 + 16, bb + w * 2048 + 1024);                  \
        GLOAD_LDS16(sx2 + (c) * 128,      bb + 8192 + w * 2048);                  \
        GLOAD_LDS16(sx2 + (c) * 128 + 16, bb + 8192 + w * 2048 + 1024);           \
        GLOAD_LDS16(wfb + (c) * 4096 + w * 1024 + l * 16, bb + 16384 + w * 1024); \
    }

#define COMPUTE(c)                                                                \
    {                                                                             \
        const char* bb = xs + ((c) & 3) * 20480;                                  \
        f16x8 B0 = *(const f16x8*)(bb + 16384 + l * 16);                          \
        f16x8 B1 = *(const f16x8*)(bb + 16384 + 1024 + l * 16);                   \
        f16x8 B2 = *(const f16x8*)(bb + 16384 + 2048 + l * 16);                   \
        f16x8 B3 = *(const f16x8*)(bb + 16384 + 3072 + l * 16);                   \
        float4 xa = *(const float4*)(bb + g * 2048 + rl16);                       \
        float4 xb = *(const float4*)(bb + g * 2048 + 1024 + rl16);                \
        f16x8 a;                                                                  \
        a[0] = (f16)xa.x; a[1] = (f16)xa.y; a[2] = (f16)xa.z; a[3] = (f16)xa.w;   \
        a[4] = (f16)xb.x; a[5] = (f16)xb.y; a[6] = (f16)xb.z; a[7] = (f16)xb.w;   \
        p00 = __builtin_amdgcn_mfma_f32_16x16x32_f16(a, B0, p00, 0, 0, 0);        \
        p01 = __builtin_amdgcn_mfma_f32_16x16x32_f16(a, B1, p01, 0, 0, 0);        \
        p02 = __builtin_amdgcn_mfma_f32_16x16x32_f16(a, B2, p02, 0, 0, 0);        \
        p03 = __builtin_amdgcn_mfma_f32_16x16x32_f16(a, B3, p03, 0, 0, 0);        \
        float4 ya = *(const float4*)(bb + 8192 + g * 2048 + rl16);                \
        float4 yb = *(const float4*)(bb + 8192 + g * 2048 + 1024 + rl16);         \
        a[0] = (f16)ya.x; a[1] = (f16)ya.y; a[2] = (f16)ya.z; a[3] = (f16)ya.w;   \
        a[4] = (f16)yb.x; a[5] = (f16)yb.y; a[6] = (f16)yb.z; a[7] = (f16)yb.w;   \
        p10 = __builtin_amdgcn_mfma_f32_16x16x32_f16(a, B0, p10, 0, 0, 0);        \
        p11 = __builtin_amdgcn_mfma_f32_16x16x32_f16(a, B1, p11, 0, 0, 0);        \
        p12 = __builtin_amdgcn_mfma_f32_16x16x32_f16(a, B2, p12, 0, 0, 0);        \
        p13 = __builtin_amdgcn_mfma_f32_16x16x32_f16(a, B3, p13, 0, 0, 0);        \
    }

// counted wait (never 0 in steady state) + raw barrier (no implicit vmcnt drain)
#define ITER(c, WN)                                         \
    asm volatile("s_waitcnt vmcnt(" WN ")" ::: "memory");   \
    __builtin_amdgcn_s_barrier();                           \
    if ((c) + 3 < 16) STAGE((c) + 3)                        \
    COMPUTE(c)

    STAGE(0) STAGE(1) STAGE(2)    // 15 DMA ops in flight
    ITER(0, "10")  ITER(1, "10")  ITER(2, "10")  ITER(3, "10")
    ITER(4, "10")  ITER(5, "10")  ITER(6, "10")  ITER(7, "10")
    ITER(8, "10")  ITER(9, "10")  ITER(10, "10") ITER(11, "10")
    ITER(12, "10") ITER(13, "10") ITER(14, "5")  ITER(15, "0")
#undef ITER
#undef COMPUTE
#undef STAGE

    // epilogue: accs -> LDS f16 tile [64 rows][128 f16] ([j*2+pass] interleave)
    __syncthreads();
    {
        f16* tile = (f16*)xs;
        const int colj = l & 15;
        const int rbase = w * 16 + g * 4;
#pragma unroll
        for (int j = 0; j < 4; ++j) {
            f16* tp = tile + (rbase + j) * 128 + colj * 2;
            tp[0]  = (f16)p00[j];
            tp[1]  = (f16)p10[j];
            tp[32] = (f16)p01[j];
            tp[33] = (f16)p11[j];
            tp[64] = (f16)p02[j];
            tp[65] = (f16)p12[j];
            tp[96] = (f16)p03[j];
            tp[97] = (f16)p13[j];
        }
        __syncthreads();
        const int row = t >> 2;            // 4 threads per 256B row
        const int gm = m0 + row;
        if (gm < n_nodes) {
            const float4* sp = reinterpret_cast<const float4*>(xs + row * 256 + (t & 3) * 64);
            float4* dp = reinterpret_cast<float4*>((char*)H + (size_t)gm * 256 + (t & 3) * 64);
#pragma unroll
            for (int q = 0; q < 4; ++q) dp[q] = sp[q];   // 64B per thread
        }
    }
}

// per-node wave gather, BOTH passes at once; 4-deep load pipeline.
// h layout [node][j*2+pass]: lane loads f16x2 = both passes of feature `lane`.
__global__ __launch_bounds__(256) void agg_both_kernel(const int* __restrict__ ptr,
                                                       const int2* __restrict__ ebin,
                                                       const f16* __restrict__ h,
                                                       const float* __restrict__ gbias,
                                                       const float* __restrict__ wsum,
                                                       const float* __restrict__ prelu_a,
                                                       float* __restrict__ z,
                                                       int n_nodes) {
    const int lane = threadIdx.x & 63;
    const int wv = threadIdx.x >> 6;
    const int n = blockIdx.x * 4 + wv;
    if (n >= n_nodes) return;
    const f16x2* hv = reinterpret_cast<const f16x2*>(h) + lane;
    const int p0 = __builtin_amdgcn_readfirstlane(ptr[n]);
    const int p1 = __builtin_amdgcn_readfirstlane(ptr[n + 1]);
    float acc1 = 0.f, acc2 = 0.f;
    int i = p0;
    for (; i + 3 < p1; i += 4) {
        int2 e0 = ebin[i];
        int2 e1 = ebin[i + 1];
        int2 e2 = ebin[i + 2];
        int2 e3 = ebin[i + 3];
        f16x2 h0 = hv[(size_t)e0.y * HDIM];
        f16x2 h1 = hv[(size_t)e1.y * HDIM];
        f16x2 h2 = hv[(size_t)e2.y * HDIM];
        f16x2 h3 = hv[(size_t)e3.y * HDIM];
        float w0 = __int_as_float(e0.x), w1 = __int_as_float(e1.x);
        float w2 = __int_as_float(e2.x), w3 = __int_as_float(e3.x);
        acc1 = fmaf(w0, (float)h0[0], acc1);
        acc2 = fmaf(w0, (float)h0[1], acc2);
        acc1 = fmaf(w1, (float)h1[0], acc1);
        acc2 = fmaf(w1, (float)h1[1], acc2);
        acc1 = fmaf(w2, (float)h2[0], acc1);
        acc2 = fmaf(w2, (float)h2[1], acc2);
        acc1 = fmaf(w3, (float)h3[0], acc1);
        acc2 = fmaf(w3, (float)h3[1], acc2);
    }
    for (; i < p1; ++i) {
        int2 e0 = ebin[i];
        f16x2 h0 = hv[(size_t)e0.y * HDIM];
        float w0 = __int_as_float(e0.x);
        acc1 = fmaf(w0, (float)h0[0], acc1);
        acc2 = fmaf(w0, (float)h0[1], acc2);
    }
    const float a = prelu_a[0];
    const float gb = gbias[lane];
    const float wl = wsum[lane];
    float v1 = acc1 + gb;
    float v2 = acc2 + gb;
    v1 = (v1 >= 0.f) ? v1 : a * v1;
    v2 = (v2 >= 0.f) ? v2 : a * v2;
    float q1 = v1 * wl;
    float q2 = v2 * wl;
#pragma unroll
    for (int m = 32; m >= 1; m >>= 1) {
        q1 += __shfl_xor(q1, m, 64);
        q2 += __shfl_xor(q2, m, 64);
    }
    if (lane == 0) {
        z[n] = q1 + wsum[HDIM];
        z[n + n_nodes] = q2 + wsum[HDIM];
    }
}

extern "C" void kernel_launch(void* const* d_in, const int* in_sizes, int n_in,
                              void* d_out, int out_size, void* d_ws, size_t ws_size,
                              hipStream_t stream) {
    const float* x1    = (const float*)d_in[0];
    const float* x2    = (const float*)d_in[1];
    const int*   erow  = (const int*)d_in[2];
    const int*   ecol  = (const int*)d_in[3];
    const float* ew    = (const float*)d_in[4];
    const float* fcw   = (const float*)d_in[5];
    const float* gbias = (const float*)d_in[6];
    const float* pa    = (const float*)d_in[7];
    const float* linw  = (const float*)d_in[8];
    const float* linb  = (const float*)d_in[9];
    float* out = (float*)d_out;

    const int n_nodes = in_sizes[0] / F_IN;   // 100000
    const int n_edges = in_sizes[2];          // 1600000
    const int NB = (n_nodes + RWIDTH - 1) >> RSHIFT;   // 782

    // workspace layout
    f16*   h16  = (f16*)d_ws;                           // n_nodes*128 f16 (both passes)
    f16*   wf   = h16 + (size_t)n_nodes * 2 * HDIM;     // 64*512 f16
    int2*  etmp = (int2*)(wf + 64 * F_IN);              // n_edges int2
    int2*  ebin = etmp + n_edges;                       // n_edges int2
    int*   bh   = (int*)(ebin + n_edges);               // MAXNB
    int*   boff = bh + MAXNB;                           // MAXNB+1
    int*   gcur = boff + MAXNB + 1;                     // MAXNB
    int*   ptr  = gcur + MAXNB;                         // n_nodes+1
    float* wsum = (float*)(ptr + n_nodes + 1);          // 65 f32

    prep_kernel<<<1, 64, 0, stream>>>(linw, linb, wsum);
    prep_w16_kernel<<<16, 256, 0, stream>>>(fcw, wf);

    zero_int_kernel<<<(NB + 255) / 256, 256, 0, stream>>>(bh, NB);
    bhist_kernel<<<256, 256, 0, stream>>>(erow, bh, n_edges, NB);
    bscan_kernel<<<1, 1024, 0, stream>>>(bh, boff, gcur, ptr, NB, n_nodes, n_edges);
    part_kernel<<<(n_edges + CHUNK - 1) / CHUNK, 256, 0, stream>>>(erow, ecol, ew, gcur,
                                                                   etmp, n_edges, NB);
    bsort_kernel<<<NB, 256, 0, stream>>>(boff, etmp, ebin, ptr, n_nodes);

    const int gemm_grid = (n_nodes + 63) / 64;
    const int fin_grid  = (n_nodes + 3) / 4;
    gemm_both_kernel<<<gemm_grid, 256, 0, stream>>>(x1, x2, wf, h16, n_nodes);
    agg_both_kernel<<<fin_grid, 256, 0, stream>>>(ptr, ebin, h16, gbias, wsum, pa,
                                                  out, n_nodes);
}